// Round 1
// baseline (310.276 us; speedup 1.0000x reference)
//
#include <hip/hip_runtime.h>
#include <cstdint>
#include <cstddef>

typedef unsigned short u16;
typedef unsigned int u32;
typedef __bf16 bf16x8 __attribute__((ext_vector_type(8)));
typedef float f32x4 __attribute__((ext_vector_type(4)));

#define DEVI static __device__ __forceinline__

// round-to-nearest-even fp32 -> bf16
DEVI u16 f2bf(float f) {
  u32 u = __builtin_bit_cast(u32, f);
  u = (u + 0x7fffu + ((u >> 16) & 1u)) >> 16;
  return (u16)u;
}

// async global->LDS, 16B per lane. LDS dest is wave-uniform base + lane*16.
DEVI void gll16(const void* gsrc, const void* ldst) {
  __builtin_amdgcn_global_load_lds(
      (const __attribute__((address_space(1))) u32*)(uintptr_t)gsrc,
      (__attribute__((address_space(3))) u32*)(u32)(uintptr_t)ldst, 16, 0, 0);
}

DEVI float wredsum(float v) {
  v += __shfl_xor(v, 32); v += __shfl_xor(v, 16); v += __shfl_xor(v, 8);
  v += __shfl_xor(v, 4);  v += __shfl_xor(v, 2);  v += __shfl_xor(v, 1);
  return v;
}

// ---------------- transpose + cvt: fp32 [R][C] -> bf16 [C][R] ----------------
__global__ __launch_bounds__(256) void k_tcvt(const float* __restrict__ in, u16* __restrict__ out,
                                              int R, int C, long in_z, long out_z) {
  __shared__ float tile[32][33];
  const float* inp = in + (long)blockIdx.z * in_z;
  u16* outp = out + (long)blockIdx.z * out_z;
  int c0 = blockIdx.x * 32, r0 = blockIdx.y * 32;
  int tx = threadIdx.x & 31, ty = threadIdx.x >> 5;
#pragma unroll
  for (int i = 0; i < 4; ++i)
    tile[ty + i * 8][tx] = inp[(long)(r0 + ty + i * 8) * C + c0 + tx];
  __syncthreads();
#pragma unroll
  for (int i = 0; i < 4; ++i) {
    int cc = ty + i * 8;
    outp[(long)(c0 + cc) * R + r0 + tx] = f2bf(tile[tx][cc]);
  }
}

// ---------------- elementwise fp32 -> bf16 ----------------
__global__ __launch_bounds__(256) void k_cvt(const float* __restrict__ in, u16* __restrict__ out, int n4) {
  int i = blockIdx.x * 256 + threadIdx.x;
  if (i >= n4) return;
  float4 v = ((const float4*)in)[i];
  ushort4 o;
  o.x = f2bf(v.x); o.y = f2bf(v.y); o.z = f2bf(v.z); o.w = f2bf(v.w);
  ((ushort4*)out)[i] = o;
}

// ---------------- bf16 MFMA GEMM, C = A[M][K] * Bt[N][K]^T + bias ----------------
// m97 structure: 128x128 tile, BK=32, 4 waves, 4x4 16x16x32 frags/wave,
// global_load_lds width-16 staging, 2 barriers per K-step.
// EPI: 0 = fp32 out, 1 = bf16 out, 2 = exact-GELU then bf16 out
template <int EPI>
__global__ __launch_bounds__(256) void k_gemm(const u16* __restrict__ A, const u16* __restrict__ Bt,
                                              const float* __restrict__ bias, void* __restrict__ Cout,
                                              int M, int N, int K) {
  __shared__ __align__(16) u16 As[128 * 32];
  __shared__ __align__(16) u16 Bs[128 * 32];
  const int tid = threadIdx.x;
  const int lane = tid & 63, wid = tid >> 6;
  const int wr = wid >> 1, wc = wid & 1;
  const int g = lane >> 4, r16 = lane & 15;
  const int row0 = blockIdx.y * 128, col0 = blockIdx.x * 128;

  f32x4 acc[4][4];
#pragma unroll
  for (int i = 0; i < 4; ++i)
#pragma unroll
    for (int j = 0; j < 4; ++j) acc[i][j] = {0.f, 0.f, 0.f, 0.f};

  const int arow = tid >> 2;          // 0..63 (iter 1 adds 64)
  const int acolb = (tid & 3) * 16;   // byte offset within 64B row

  for (int k0 = 0; k0 < K; k0 += 32) {
#pragma unroll
    for (int it = 0; it < 2; ++it) {
      int rowa = it * 64 + arow;
      gll16((const char*)A + ((size_t)(row0 + rowa) * K + k0) * 2 + acolb,
            (const char*)As + it * 4096 + wid * 1024);
      gll16((const char*)Bt + ((size_t)(col0 + rowa) * K + k0) * 2 + acolb,
            (const char*)Bs + it * 4096 + wid * 1024);
    }
    __syncthreads();
    bf16x8 aF[4], bF[4];
#pragma unroll
    for (int mi = 0; mi < 4; ++mi)
      aF[mi] = *(const bf16x8*)(As + (wr * 64 + mi * 16 + r16) * 32 + g * 8);
#pragma unroll
    for (int ni = 0; ni < 4; ++ni)
      bF[ni] = *(const bf16x8*)(Bs + (wc * 64 + ni * 16 + r16) * 32 + g * 8);
#pragma unroll
    for (int mi = 0; mi < 4; ++mi)
#pragma unroll
      for (int ni = 0; ni < 4; ++ni)
        acc[mi][ni] = __builtin_amdgcn_mfma_f32_16x16x32_bf16(aF[mi], bF[ni], acc[mi][ni], 0, 0, 0);
    __syncthreads();
  }

#pragma unroll
  for (int ni = 0; ni < 4; ++ni) {
    int col = col0 + wc * 64 + ni * 16 + r16;
    float bv = bias ? bias[col] : 0.f;
#pragma unroll
    for (int mi = 0; mi < 4; ++mi) {
      int rowb = row0 + wr * 64 + mi * 16 + g * 4;
#pragma unroll
      for (int j = 0; j < 4; ++j) {
        float v = acc[mi][ni][j] + bv;
        size_t off = (size_t)(rowb + j) * N + col;
        if (EPI == 0) {
          ((float*)Cout)[off] = v;
        } else if (EPI == 1) {
          ((u16*)Cout)[off] = f2bf(v);
        } else {
          float gl = 0.5f * v * (1.f + erff(v * 0.70710678118f));
          ((u16*)Cout)[off] = f2bf(gl);
        }
      }
    }
  }
}

// ---------------- build V^T: qkvb[token][2048+h*64+p] -> vt[(b,h)][p][s] ----------------
__global__ __launch_bounds__(256) void k_build_vt(const u16* __restrict__ qkvb, u16* __restrict__ vt) {
  __shared__ u16 tile[32][33];
  int z = blockIdx.z, b = z >> 4, h = z & 15;
  int p0 = blockIdx.x * 32, s0 = blockIdx.y * 32;
  int tx = threadIdx.x & 31, ty = threadIdx.x >> 5;
#pragma unroll
  for (int i = 0; i < 4; ++i) {
    int s = s0 + ty + i * 8;
    tile[ty + i * 8][tx] = qkvb[(size_t)(b * 512 + s) * 3072 + 2048 + h * 64 + p0 + tx];
  }
  __syncthreads();
#pragma unroll
  for (int i = 0; i < 4; ++i) {
    int p = ty + i * 8;
    vt[((size_t)z * 64 + p0 + p) * 512 + s0 + tx] = tile[tx][p];
  }
}

// ---------------- fused flash attention ----------------
// grid (S/64, B*H). 4 waves, each wave owns 16 q-rows. K/V^T staged to LDS with
// XOR swizzle via pre-swizzled global source (byte ^= (row&7)<<4 within 128B rows).
__global__ __launch_bounds__(256) void k_attn(const u16* __restrict__ qkvb, const u16* __restrict__ vt,
                                              u16* __restrict__ ctxb) {
  __shared__ __align__(16) u16 Qs[64 * 64];
  __shared__ __align__(16) u16 Ks[64 * 64];
  __shared__ __align__(16) u16 Vts[64 * 64];
  __shared__ __align__(16) u16 Ps[4 * 16 * 64];
  const int tid = threadIdx.x, lane = tid & 63, wid = tid >> 6;
  const int g = lane >> 4, r16 = lane & 15;
  const int z = blockIdx.y, b = z >> 4, h = z & 15;
  const int qt = blockIdx.x;
  const float CF = 0.125f * 1.44269504089f;  // 1/sqrt(64) * log2(e)

  // stage Q tile [64 q][64 p], swizzled
#pragma unroll
  for (int it = 0; it < 2; ++it) {
    int q = it * 4096 + tid * 16;
    int row = q >> 7, colb = q & 127;
    int scol = colb ^ ((row & 7) << 4);
    gll16((const char*)qkvb + ((size_t)(b * 512 + qt * 64 + row) * 3072 + h * 64) * 2 + scol,
          (const char*)Qs + it * 4096 + wid * 1024);
  }
  __syncthreads();
  bf16x8 aq[2];
  {
    int rowl = wid * 16 + r16;
#pragma unroll
    for (int kk = 0; kk < 2; ++kk)
      aq[kk] = *(const bf16x8*)(Qs + rowl * 64 + ((kk * 32 + g * 8) ^ ((rowl & 7) << 3)));
  }

  f32x4 o[4];
#pragma unroll
  for (int pi = 0; pi < 4; ++pi) o[pi] = {0.f, 0.f, 0.f, 0.f};
  float m4[4], l4[4];
#pragma unroll
  for (int j = 0; j < 4; ++j) { m4[j] = -1e30f; l4[j] = 0.f; }

  for (int kt = 0; kt < 8; ++kt) {
    // stage K tile [64 key][64 p] and Vt tile [64 p][64 key], swizzled
#pragma unroll
    for (int it = 0; it < 2; ++it) {
      int q = it * 4096 + tid * 16;
      int row = q >> 7, colb = q & 127;
      int scol = colb ^ ((row & 7) << 4);
      gll16((const char*)qkvb + ((size_t)(b * 512 + kt * 64 + row) * 3072 + 1024 + h * 64) * 2 + scol,
            (const char*)Ks + it * 4096 + wid * 1024);
      gll16((const char*)vt + ((size_t)(z * 64 + row) * 512 + kt * 64) * 2 + scol,
            (const char*)Vts + it * 4096 + wid * 1024);
    }
    __syncthreads();

    // S = Q K^T (raw scores; 1/8 folded into CF)
    f32x4 s[4];
#pragma unroll
    for (int nj = 0; nj < 4; ++nj) s[nj] = {0.f, 0.f, 0.f, 0.f};
#pragma unroll
    for (int kk = 0; kk < 2; ++kk) {
#pragma unroll
      for (int nj = 0; nj < 4; ++nj) {
        int rowk = nj * 16 + r16;
        bf16x8 bk = *(const bf16x8*)(Ks + rowk * 64 + ((kk * 32 + g * 8) ^ ((rowk & 7) << 3)));
        s[nj] = __builtin_amdgcn_mfma_f32_16x16x32_bf16(aq[kk], bk, s[nj], 0, 0, 0);
      }
    }

    // online softmax (16-lane-group row reduce), write P~ (bf16) to per-wave LDS
    float scale[4];
#pragma unroll
    for (int j = 0; j < 4; ++j) {
      float pm = fmaxf(fmaxf(s[0][j], s[1][j]), fmaxf(s[2][j], s[3][j]));
      pm = fmaxf(pm, __shfl_xor(pm, 1));
      pm = fmaxf(pm, __shfl_xor(pm, 2));
      pm = fmaxf(pm, __shfl_xor(pm, 4));
      pm = fmaxf(pm, __shfl_xor(pm, 8));
      float mn = fmaxf(m4[j], pm);
      scale[j] = exp2f((m4[j] - mn) * CF);
      m4[j] = mn;
      int rowp = g * 4 + j;
      u16* pbase = Ps + wid * 1024 + rowp * 64;
      int sw = (rowp & 7) << 3;
      float ps = 0.f;
#pragma unroll
      for (int nj = 0; nj < 4; ++nj) {
        float p = exp2f((s[nj][j] - mn) * CF);
        ps += p;
        pbase[(nj * 16 + r16) ^ sw] = f2bf(p);
      }
      ps += __shfl_xor(ps, 1); ps += __shfl_xor(ps, 2);
      ps += __shfl_xor(ps, 4); ps += __shfl_xor(ps, 8);
      l4[j] = l4[j] * scale[j] + ps;
    }
#pragma unroll
    for (int pi = 0; pi < 4; ++pi)
#pragma unroll
      for (int j = 0; j < 4; ++j) o[pi][j] *= scale[j];

    asm volatile("s_waitcnt lgkmcnt(0)" ::: "memory");

    // O += P~ V
#pragma unroll
    for (int kk = 0; kk < 2; ++kk) {
      bf16x8 ap = *(const bf16x8*)(Ps + wid * 1024 + r16 * 64 + ((kk * 32 + g * 8) ^ ((r16 & 7) << 3)));
#pragma unroll
      for (int pi = 0; pi < 4; ++pi) {
        int rowv = pi * 16 + r16;
        bf16x8 bv = *(const bf16x8*)(Vts + rowv * 64 + ((kk * 32 + g * 8) ^ ((rowv & 7) << 3)));
        o[pi] = __builtin_amdgcn_mfma_f32_16x16x32_bf16(ap, bv, o[pi], 0, 0, 0);
      }
    }
    __syncthreads();
  }

#pragma unroll
  for (int j = 0; j < 4; ++j) {
    float inv = 1.f / l4[j];
    int token = b * 512 + qt * 64 + wid * 16 + g * 4 + j;
#pragma unroll
    for (int pi = 0; pi < 4; ++pi)
      ctxb[(size_t)token * 1024 + h * 64 + pi * 16 + r16] = f2bf(o[pi][j] * inv);
  }
}

// ---------------- fused residual + LayerNorm (optional bf16 copy out) ----------------
__global__ __launch_bounds__(256) void k_ln(const float* __restrict__ a, const float* __restrict__ res,
                                            const float* __restrict__ gamma, const float* __restrict__ beta,
                                            float* __restrict__ outf, u16* __restrict__ outb) {
  __shared__ float sb[8];
  int row = blockIdx.x, t = threadIdx.x, lane = t & 63, wid = t >> 6;
  const float* pa = a + (size_t)row * 1024;
  const float* pr = res + (size_t)row * 1024;
  float v[4];
  float s = 0.f;
#pragma unroll
  for (int i = 0; i < 4; ++i) { v[i] = pa[i * 256 + t] + pr[i * 256 + t]; s += v[i]; }
  s = wredsum(s);
  if (lane == 0) sb[wid] = s;
  __syncthreads();
  float mu = (sb[0] + sb[1] + sb[2] + sb[3]) * (1.f / 1024.f);
  float q = 0.f;
#pragma unroll
  for (int i = 0; i < 4; ++i) { float d = v[i] - mu; q += d * d; }
  q = wredsum(q);
  if (lane == 0) sb[4 + wid] = q;
  __syncthreads();
  float rstd = rsqrtf((sb[4] + sb[5] + sb[6] + sb[7]) * (1.f / 1024.f) + 1e-5f);
#pragma unroll
  for (int i = 0; i < 4; ++i) {
    int c = i * 256 + t;
    float ov = (v[i] - mu) * rstd * gamma[c] + beta[c];
    outf[(size_t)row * 1024 + c] = ov;
    if (outb) outb[(size_t)row * 1024 + c] = f2bf(ov);
  }
}

// ---------------- orchestration ----------------
// Workspace map (MB):
//   [0,6)   wqkvb  bf16 [3072][1024] (B^T)
//   [6,8)   woutb  bf16 [1024][1024]
//   [8,16)  wffn1b bf16 [4096][1024]
//   [16,24) wffn2b bf16 [1024][4096]
//   [24,32) xb -> ctxb -> r1b (bf16, 4096x1024)
//   [32,56) qkvb bf16 [4096][3072];  [32,64) later: h bf16 [4096][4096]
//   [56,64) vt bf16 [128][64][512]
//   [64,80) attn_out fp32 -> ffn_out fp32 [4096][1024]
//   r1 fp32 lives in d_out.   Peak: 80 MB.
extern "C" void kernel_launch(void* const* d_in, const int* in_sizes, int n_in,
                              void* d_out, int out_size, void* d_ws, size_t ws_size,
                              hipStream_t stream) {
  const float* x      = (const float*)d_in[0];
  const float* w_qkv  = (const float*)d_in[1];
  const float* b_qkv  = (const float*)d_in[2];
  const float* w_out  = (const float*)d_in[3];
  const float* b_out  = (const float*)d_in[4];
  const float* ln1s   = (const float*)d_in[5];
  const float* ln1b   = (const float*)d_in[6];
  const float* w_ffn1 = (const float*)d_in[7];
  const float* b_ffn1 = (const float*)d_in[8];
  const float* w_ffn2 = (const float*)d_in[9];
  const float* b_ffn2 = (const float*)d_in[10];
  const float* ln2s   = (const float*)d_in[11];
  const float* ln2b   = (const float*)d_in[12];

  char* ws = (char*)d_ws;
  const size_t MB = 1024 * 1024;
  u16* wqkvb   = (u16*)(ws + 0 * MB);
  u16* woutb   = (u16*)(ws + 6 * MB);
  u16* wffn1b  = (u16*)(ws + 8 * MB);
  u16* wffn2b  = (u16*)(ws + 16 * MB);
  u16* xb      = (u16*)(ws + 24 * MB);
  u16* ctxb    = xb;
  u16* r1b     = xb;
  u16* qkvb    = (u16*)(ws + 32 * MB);
  u16* hb      = (u16*)(ws + 32 * MB);
  u16* vt      = (u16*)(ws + 56 * MB);
  float* attn_out = (float*)(ws + 64 * MB);
  float* ffn_out  = (float*)(ws + 64 * MB);
  float* r1    = (float*)d_out;
  float* outp  = (float*)d_out;

  // pack weights (transpose to [N][K] bf16)
  k_tcvt<<<dim3(32, 32, 3), 256, 0, stream>>>(w_qkv, wqkvb, 1024, 1024, 1024 * 1024, 1024 * 1024);
  k_tcvt<<<dim3(32, 32, 1), 256, 0, stream>>>(w_out, woutb, 1024, 1024, 0, 0);
  k_tcvt<<<dim3(128, 32, 1), 256, 0, stream>>>(w_ffn1, wffn1b, 1024, 4096, 0, 0);
  k_tcvt<<<dim3(32, 128, 1), 256, 0, stream>>>(w_ffn2, wffn2b, 4096, 1024, 0, 0);
  k_cvt<<<4096, 256, 0, stream>>>(x, xb, 1048576);

  // qkv = x @ w_qkv + b_qkv   (bf16 out)
  k_gemm<1><<<dim3(24, 32), 256, 0, stream>>>(xb, wqkvb, b_qkv, qkvb, 4096, 3072, 1024);
  k_build_vt<<<dim3(2, 16, 128), 256, 0, stream>>>(qkvb, vt);
  k_attn<<<dim3(8, 128), 256, 0, stream>>>(qkvb, vt, ctxb);
  // attn_out = ctx @ w_out + b_out  (fp32 out)
  k_gemm<0><<<dim3(8, 32), 256, 0, stream>>>(ctxb, woutb, b_out, attn_out, 4096, 1024, 1024);
  // r1 = LN(x + attn_out) -> fp32 (d_out) + bf16
  k_ln<<<4096, 256, 0, stream>>>(attn_out, x, ln1s, ln1b, r1, r1b);
  // h = gelu(r1 @ w_ffn1 + b_ffn1)  (bf16 out)
  k_gemm<2><<<dim3(32, 32), 256, 0, stream>>>(r1b, wffn1b, b_ffn1, hb, 4096, 4096, 1024);
  // ffn_out = h @ w_ffn2 + b_ffn2  (fp32 out)
  k_gemm<0><<<dim3(8, 32), 256, 0, stream>>>(hb, wffn2b, b_ffn2, ffn_out, 4096, 1024, 4096);
  // out = LN(r1 + ffn_out)
  k_ln<<<4096, 256, 0, stream>>>(ffn_out, r1, ln2s, ln2b, outp, (u16*)nullptr);
}

// Round 2
// 275.578 us; speedup vs baseline: 1.1259x; 1.1259x over previous
//
#include <hip/hip_runtime.h>
#include <cstdint>
#include <cstddef>

typedef unsigned short u16;
typedef unsigned int u32;
typedef __bf16 bf16x8 __attribute__((ext_vector_type(8)));
typedef float f32x4 __attribute__((ext_vector_type(4)));

#define DEVI static __device__ __forceinline__

// round-to-nearest-even fp32 -> bf16
DEVI u16 f2bf(float f) {
  u32 u = __builtin_bit_cast(u32, f);
  u = (u + 0x7fffu + ((u >> 16) & 1u)) >> 16;
  return (u16)u;
}

// async global->LDS, 16B per lane. LDS dest is wave-uniform base + lane*16.
DEVI void gll16(const void* gsrc, const void* ldst) {
  __builtin_amdgcn_global_load_lds(
      (const __attribute__((address_space(1))) u32*)(uintptr_t)gsrc,
      (__attribute__((address_space(3))) u32*)(u32)(uintptr_t)ldst, 16, 0, 0);
}

DEVI float wredsum(float v) {
  v += __shfl_xor(v, 32); v += __shfl_xor(v, 16); v += __shfl_xor(v, 8);
  v += __shfl_xor(v, 4);  v += __shfl_xor(v, 2);  v += __shfl_xor(v, 1);
  return v;
}

// ---------------- transpose + cvt: fp32 [R][C] -> bf16 [C][R] ----------------
__global__ __launch_bounds__(256) void k_tcvt(const float* __restrict__ in, u16* __restrict__ out,
                                              int R, int C, long in_z, long out_z) {
  __shared__ float tile[32][33];
  const float* inp = in + (long)blockIdx.z * in_z;
  u16* outp = out + (long)blockIdx.z * out_z;
  int c0 = blockIdx.x * 32, r0 = blockIdx.y * 32;
  int tx = threadIdx.x & 31, ty = threadIdx.x >> 5;
#pragma unroll
  for (int i = 0; i < 4; ++i)
    tile[ty + i * 8][tx] = inp[(long)(r0 + ty + i * 8) * C + c0 + tx];
  __syncthreads();
#pragma unroll
  for (int i = 0; i < 4; ++i) {
    int cc = ty + i * 8;
    outp[(long)(c0 + cc) * R + r0 + tx] = f2bf(tile[tx][cc]);
  }
}

// ---------------- elementwise fp32 -> bf16 ----------------
__global__ __launch_bounds__(256) void k_cvt(const float* __restrict__ in, u16* __restrict__ out, int n4) {
  int i = blockIdx.x * 256 + threadIdx.x;
  if (i >= n4) return;
  float4 v = ((const float4*)in)[i];
  ushort4 o;
  o.x = f2bf(v.x); o.y = f2bf(v.y); o.z = f2bf(v.z); o.w = f2bf(v.w);
  ((ushort4*)out)[i] = o;
}

// ---------------- bf16 MFMA GEMM, C = A[M][K] * Bt[N][K]^T + bias ----------------
// m97 structure: 128x128 tile, BK=32, 4 waves, 4x4 16x16x32 frags/wave,
// global_load_lds width-16 staging, 2 barriers per K-step.
// Split-K: blockIdx.z selects K-chunk [z*Kc, (z+1)*Kc); fp32 output goes to
// Cout + z*pofs (partials summed by the following LN kernel).
// EPI: 0 = fp32 out, 1 = bf16 out, 2 = exact-GELU then bf16 out
template <int EPI>
__global__ __launch_bounds__(256) void k_gemm(const u16* __restrict__ A, const u16* __restrict__ Bt,
                                              const float* __restrict__ bias, void* __restrict__ Cout,
                                              long pofs, int M, int N, int K, int Kc) {
  __shared__ __align__(16) u16 As[128 * 32];
  __shared__ __align__(16) u16 Bs[128 * 32];
  const int tid = threadIdx.x;
  const int lane = tid & 63, wid = tid >> 6;
  const int wr = wid >> 1, wc = wid & 1;
  const int g = lane >> 4, r16 = lane & 15;
  const int row0 = blockIdx.y * 128, col0 = blockIdx.x * 128;
  const int kbeg = blockIdx.z * Kc, kend = kbeg + Kc;

  f32x4 acc[4][4];
#pragma unroll
  for (int i = 0; i < 4; ++i)
#pragma unroll
    for (int j = 0; j < 4; ++j) acc[i][j] = {0.f, 0.f, 0.f, 0.f};

  const int arow = tid >> 2;          // 0..63 (iter 1 adds 64)
  const int acolb = (tid & 3) * 16;   // byte offset within 64B row

  for (int k0 = kbeg; k0 < kend; k0 += 32) {
#pragma unroll
    for (int it = 0; it < 2; ++it) {
      int rowa = it * 64 + arow;
      gll16((const char*)A + ((size_t)(row0 + rowa) * K + k0) * 2 + acolb,
            (const char*)As + it * 4096 + wid * 1024);
      gll16((const char*)Bt + ((size_t)(col0 + rowa) * K + k0) * 2 + acolb,
            (const char*)Bs + it * 4096 + wid * 1024);
    }
    __syncthreads();
    bf16x8 aF[4], bF[4];
#pragma unroll
    for (int mi = 0; mi < 4; ++mi)
      aF[mi] = *(const bf16x8*)(As + (wr * 64 + mi * 16 + r16) * 32 + g * 8);
#pragma unroll
    for (int ni = 0; ni < 4; ++ni)
      bF[ni] = *(const bf16x8*)(Bs + (wc * 64 + ni * 16 + r16) * 32 + g * 8);
#pragma unroll
    for (int mi = 0; mi < 4; ++mi)
#pragma unroll
      for (int ni = 0; ni < 4; ++ni)
        acc[mi][ni] = __builtin_amdgcn_mfma_f32_16x16x32_bf16(aF[mi], bF[ni], acc[mi][ni], 0, 0, 0);
    __syncthreads();
  }

  float* outf = (float*)Cout + (long)blockIdx.z * pofs;
#pragma unroll
  for (int ni = 0; ni < 4; ++ni) {
    int col = col0 + wc * 64 + ni * 16 + r16;
    float bv = bias ? bias[col] : 0.f;
#pragma unroll
    for (int mi = 0; mi < 4; ++mi) {
      int rowb = row0 + wr * 64 + mi * 16 + g * 4;
#pragma unroll
      for (int j = 0; j < 4; ++j) {
        float v = acc[mi][ni][j] + bv;
        size_t off = (size_t)(rowb + j) * N + col;
        if (EPI == 0) {
          outf[off] = v;
        } else if (EPI == 1) {
          ((u16*)Cout)[off] = f2bf(v);
        } else {
          float gl = 0.5f * v * (1.f + erff(v * 0.70710678118f));
          ((u16*)Cout)[off] = f2bf(gl);
        }
      }
    }
  }
}

// ---------------- build V^T: qkvb[token][2048+h*64+p] -> vt[(b,h)][p][s] ----------------
__global__ __launch_bounds__(256) void k_build_vt(const u16* __restrict__ qkvb, u16* __restrict__ vt) {
  __shared__ u16 tile[32][33];
  int z = blockIdx.z, b = z >> 4, h = z & 15;
  int p0 = blockIdx.x * 32, s0 = blockIdx.y * 32;
  int tx = threadIdx.x & 31, ty = threadIdx.x >> 5;
#pragma unroll
  for (int i = 0; i < 4; ++i) {
    int s = s0 + ty + i * 8;
    tile[ty + i * 8][tx] = qkvb[(size_t)(b * 512 + s) * 3072 + 2048 + h * 64 + p0 + tx];
  }
  __syncthreads();
#pragma unroll
  for (int i = 0; i < 4; ++i) {
    int p = ty + i * 8;
    vt[((size_t)z * 64 + p0 + p) * 512 + s0 + tx] = tile[tx][p];
  }
}

// ---------------- fused flash attention ----------------
// grid (S/64, B*H). 4 waves, each wave owns 16 q-rows. K/V^T staged to LDS with
// XOR swizzle via pre-swizzled global source (byte ^= (row&7)<<4 within 128B rows).
__global__ __launch_bounds__(256) void k_attn(const u16* __restrict__ qkvb, const u16* __restrict__ vt,
                                              u16* __restrict__ ctxb) {
  __shared__ __align__(16) u16 Qs[64 * 64];
  __shared__ __align__(16) u16 Ks[64 * 64];
  __shared__ __align__(16) u16 Vts[64 * 64];
  __shared__ __align__(16) u16 Ps[4 * 16 * 64];
  const int tid = threadIdx.x, lane = tid & 63, wid = tid >> 6;
  const int g = lane >> 4, r16 = lane & 15;
  const int z = blockIdx.y, b = z >> 4, h = z & 15;
  const int qt = blockIdx.x;
  const float CF = 0.125f * 1.44269504089f;  // 1/sqrt(64) * log2(e)

  // stage Q tile [64 q][64 p], swizzled
#pragma unroll
  for (int it = 0; it < 2; ++it) {
    int q = it * 4096 + tid * 16;
    int row = q >> 7, colb = q & 127;
    int scol = colb ^ ((row & 7) << 4);
    gll16((const char*)qkvb + ((size_t)(b * 512 + qt * 64 + row) * 3072 + h * 64) * 2 + scol,
          (const char*)Qs + it * 4096 + wid * 1024);
  }
  __syncthreads();
  bf16x8 aq[2];
  {
    int rowl = wid * 16 + r16;
#pragma unroll
    for (int kk = 0; kk < 2; ++kk)
      aq[kk] = *(const bf16x8*)(Qs + rowl * 64 + ((kk * 32 + g * 8) ^ ((rowl & 7) << 3)));
  }

  f32x4 o[4];
#pragma unroll
  for (int pi = 0; pi < 4; ++pi) o[pi] = {0.f, 0.f, 0.f, 0.f};
  float m4[4], l4[4];
#pragma unroll
  for (int j = 0; j < 4; ++j) { m4[j] = -1e30f; l4[j] = 0.f; }

  for (int kt = 0; kt < 8; ++kt) {
    // stage K tile [64 key][64 p] and Vt tile [64 p][64 key], swizzled
#pragma unroll
    for (int it = 0; it < 2; ++it) {
      int q = it * 4096 + tid * 16;
      int row = q >> 7, colb = q & 127;
      int scol = colb ^ ((row & 7) << 4);
      gll16((const char*)qkvb + ((size_t)(b * 512 + kt * 64 + row) * 3072 + 1024 + h * 64) * 2 + scol,
            (const char*)Ks + it * 4096 + wid * 1024);
      gll16((const char*)vt + ((size_t)(z * 64 + row) * 512 + kt * 64) * 2 + scol,
            (const char*)Vts + it * 4096 + wid * 1024);
    }
    __syncthreads();

    // S = Q K^T (raw scores; 1/8 folded into CF)
    f32x4 s[4];
#pragma unroll
    for (int nj = 0; nj < 4; ++nj) s[nj] = {0.f, 0.f, 0.f, 0.f};
#pragma unroll
    for (int kk = 0; kk < 2; ++kk) {
#pragma unroll
      for (int nj = 0; nj < 4; ++nj) {
        int rowk = nj * 16 + r16;
        bf16x8 bk = *(const bf16x8*)(Ks + rowk * 64 + ((kk * 32 + g * 8) ^ ((rowk & 7) << 3)));
        s[nj] = __builtin_amdgcn_mfma_f32_16x16x32_bf16(aq[kk], bk, s[nj], 0, 0, 0);
      }
    }

    // online softmax (16-lane-group row reduce), write P~ (bf16) to per-wave LDS
    float scale[4];
#pragma unroll
    for (int j = 0; j < 4; ++j) {
      float pm = fmaxf(fmaxf(s[0][j], s[1][j]), fmaxf(s[2][j], s[3][j]));
      pm = fmaxf(pm, __shfl_xor(pm, 1));
      pm = fmaxf(pm, __shfl_xor(pm, 2));
      pm = fmaxf(pm, __shfl_xor(pm, 4));
      pm = fmaxf(pm, __shfl_xor(pm, 8));
      float mn = fmaxf(m4[j], pm);
      scale[j] = exp2f((m4[j] - mn) * CF);
      m4[j] = mn;
      int rowp = g * 4 + j;
      u16* pbase = Ps + wid * 1024 + rowp * 64;
      int sw = (rowp & 7) << 3;
      float ps = 0.f;
#pragma unroll
      for (int nj = 0; nj < 4; ++nj) {
        float p = exp2f((s[nj][j] - mn) * CF);
        ps += p;
        pbase[(nj * 16 + r16) ^ sw] = f2bf(p);
      }
      ps += __shfl_xor(ps, 1); ps += __shfl_xor(ps, 2);
      ps += __shfl_xor(ps, 4); ps += __shfl_xor(ps, 8);
      l4[j] = l4[j] * scale[j] + ps;
    }
#pragma unroll
    for (int pi = 0; pi < 4; ++pi)
#pragma unroll
      for (int j = 0; j < 4; ++j) o[pi][j] *= scale[j];

    asm volatile("s_waitcnt lgkmcnt(0)" ::: "memory");

    // O += P~ V
#pragma unroll
    for (int kk = 0; kk < 2; ++kk) {
      bf16x8 ap = *(const bf16x8*)(Ps + wid * 1024 + r16 * 64 + ((kk * 32 + g * 8) ^ ((r16 & 7) << 3)));
#pragma unroll
      for (int pi = 0; pi < 4; ++pi) {
        int rowv = pi * 16 + r16;
        bf16x8 bv = *(const bf16x8*)(Vts + rowv * 64 + ((kk * 32 + g * 8) ^ ((rowv & 7) << 3)));
        o[pi] = __builtin_amdgcn_mfma_f32_16x16x32_bf16(ap, bv, o[pi], 0, 0, 0);
      }
    }
    __syncthreads();
  }

#pragma unroll
  for (int j = 0; j < 4; ++j) {
    float inv = 1.f / l4[j];
    int token = b * 512 + qt * 64 + wid * 16 + g * 4 + j;
#pragma unroll
    for (int pi = 0; pi < 4; ++pi)
      ctxb[(size_t)token * 1024 + h * 64 + pi * 16 + r16] = f2bf(o[pi][j] * inv);
  }
}

// ---------------- fused (2-partial sum) + bias + residual + LayerNorm ----------------
// v = a0[row] + a1[row] + res[row] + bvec[col];  out = LN(v)*gamma+beta
__global__ __launch_bounds__(256) void k_ln3(const float* __restrict__ a0, const float* __restrict__ a1,
                                             const float* __restrict__ res, const float* __restrict__ bvec,
                                             const float* __restrict__ gamma, const float* __restrict__ beta,
                                             float* __restrict__ outf, u16* __restrict__ outb) {
  __shared__ float sb[8];
  int row = blockIdx.x, t = threadIdx.x, lane = t & 63, wid = t >> 6;
  const float* p0 = a0 + (size_t)row * 1024;
  const float* p1 = a1 + (size_t)row * 1024;
  const float* pr = res + (size_t)row * 1024;
  float v[4];
  float s = 0.f;
#pragma unroll
  for (int i = 0; i < 4; ++i) {
    int c = i * 256 + t;
    v[i] = p0[c] + p1[c] + pr[c] + bvec[c];
    s += v[i];
  }
  s = wredsum(s);
  if (lane == 0) sb[wid] = s;
  __syncthreads();
  float mu = (sb[0] + sb[1] + sb[2] + sb[3]) * (1.f / 1024.f);
  float q = 0.f;
#pragma unroll
  for (int i = 0; i < 4; ++i) { float d = v[i] - mu; q += d * d; }
  q = wredsum(q);
  if (lane == 0) sb[4 + wid] = q;
  __syncthreads();
  float rstd = rsqrtf((sb[4] + sb[5] + sb[6] + sb[7]) * (1.f / 1024.f) + 1e-5f);
#pragma unroll
  for (int i = 0; i < 4; ++i) {
    int c = i * 256 + t;
    float ov = (v[i] - mu) * rstd * gamma[c] + beta[c];
    outf[(size_t)row * 1024 + c] = ov;
    if (outb) outb[(size_t)row * 1024 + c] = f2bf(ov);
  }
}

// ---------------- orchestration ----------------
// Workspace map (MB), time-multiplexed:
//   [0,6)   wqkvb  bf16 [3072][1024] (B^T)        -> later ffn2 partial p1 [0,16)
//   [6,8)   woutb  bf16 [1024][1024]
//   [8,16)  wffn1b bf16 [4096][1024]
//   [16,24) wffn2b bf16 [1024][4096]
//   [24,32) xb -> ctxb -> r1b (bf16, 4096x1024)
//   [32,56) qkvb bf16 [4096][3072] -> attn_out partial q1 [32,48) -> h bf16 [32,64)
//   [56,64) vt bf16 [128][64][512]
//   [64,80) attn_out partial q0 -> ffn2 partial p0 (fp32 [4096][1024])
//   r1 fp32 lives in d_out.   Peak: 80 MB.
extern "C" void kernel_launch(void* const* d_in, const int* in_sizes, int n_in,
                              void* d_out, int out_size, void* d_ws, size_t ws_size,
                              hipStream_t stream) {
  const float* x      = (const float*)d_in[0];
  const float* w_qkv  = (const float*)d_in[1];
  const float* b_qkv  = (const float*)d_in[2];
  const float* w_out  = (const float*)d_in[3];
  const float* b_out  = (const float*)d_in[4];
  const float* ln1s   = (const float*)d_in[5];
  const float* ln1b   = (const float*)d_in[6];
  const float* w_ffn1 = (const float*)d_in[7];
  const float* b_ffn1 = (const float*)d_in[8];
  const float* w_ffn2 = (const float*)d_in[9];
  const float* b_ffn2 = (const float*)d_in[10];
  const float* ln2s   = (const float*)d_in[11];
  const float* ln2b   = (const float*)d_in[12];

  char* ws = (char*)d_ws;
  const size_t MB = 1024 * 1024;
  u16* wqkvb   = (u16*)(ws + 0 * MB);
  u16* woutb   = (u16*)(ws + 6 * MB);
  u16* wffn1b  = (u16*)(ws + 8 * MB);
  u16* wffn2b  = (u16*)(ws + 16 * MB);
  u16* xb      = (u16*)(ws + 24 * MB);
  u16* ctxb    = xb;
  u16* r1b     = xb;
  u16* qkvb    = (u16*)(ws + 32 * MB);
  u16* hb      = (u16*)(ws + 32 * MB);
  u16* vt      = (u16*)(ws + 56 * MB);
  float* q0    = (float*)(ws + 64 * MB);   // attn_out partial z=0
  float* q1    = (float*)(ws + 32 * MB);   // attn_out partial z=1 (over dead qkvb)
  float* p0    = (float*)(ws + 64 * MB);   // ffn2 partial z=0 (over dead q0)
  float* p1    = (float*)(ws + 0 * MB);    // ffn2 partial z=1 (over dead weight packs)
  float* r1    = (float*)d_out;
  float* outp  = (float*)d_out;

  const long NEL = 4096L * 1024L;  // elements per fp32 partial (16 MB)

  // pack weights (transpose to [N][K] bf16)
  k_tcvt<<<dim3(32, 32, 3), 256, 0, stream>>>(w_qkv, wqkvb, 1024, 1024, 1024 * 1024, 1024 * 1024);
  k_tcvt<<<dim3(32, 32, 1), 256, 0, stream>>>(w_out, woutb, 1024, 1024, 0, 0);
  k_tcvt<<<dim3(128, 32, 1), 256, 0, stream>>>(w_ffn1, wffn1b, 1024, 4096, 0, 0);
  k_tcvt<<<dim3(32, 128, 1), 256, 0, stream>>>(w_ffn2, wffn2b, 4096, 1024, 0, 0);
  k_cvt<<<4096, 256, 0, stream>>>(x, xb, 1048576);

  // qkv = x @ w_qkv + b_qkv   (bf16 out)
  k_gemm<1><<<dim3(24, 32), 256, 0, stream>>>(xb, wqkvb, b_qkv, qkvb, 0, 4096, 3072, 1024, 1024);
  k_build_vt<<<dim3(2, 16, 128), 256, 0, stream>>>(qkvb, vt);
  k_attn<<<dim3(8, 128), 256, 0, stream>>>(qkvb, vt, ctxb);

  // attn_out = ctx @ w_out (split-K=2, fp32 partials q0/q1; bias folded into ln1)
  {
    long pofs = (long)(q1 - q0);  // z=1 partial lands on q1
    k_gemm<0><<<dim3(8, 32, 2), 256, 0, stream>>>(ctxb, woutb, nullptr, q0, pofs, 4096, 1024, 1024, 512);
  }
  // r1 = LN(x + q0 + q1 + b_out) -> fp32 (d_out) + bf16
  k_ln3<<<4096, 256, 0, stream>>>(q0, q1, x, b_out, ln1s, ln1b, r1, r1b);

  // h = gelu(r1 @ w_ffn1 + b_ffn1)  (bf16 out)
  k_gemm<2><<<dim3(32, 32), 256, 0, stream>>>(r1b, wffn1b, b_ffn1, hb, 0, 4096, 4096, 1024, 1024);

  // ffn_out = h @ w_ffn2 (split-K=2, fp32 partials p0/p1; bias folded into ln2)
  {
    long pofs = (long)(p1 - p0);
    k_gemm<0><<<dim3(8, 32, 2), 256, 0, stream>>>(hb, wffn2b, nullptr, p0, pofs, 4096, 1024, 4096, 2048);
  }
  // out = LN(r1 + p0 + p1 + b_ffn2)
  k_ln3<<<4096, 256, 0, stream>>>(p0, p1, r1, b_ffn2, ln2s, ln2b, outp, (u16*)nullptr);
}

// Round 3
// 245.447 us; speedup vs baseline: 1.2641x; 1.1228x over previous
//
#include <hip/hip_runtime.h>
#include <cstdint>
#include <cstddef>

typedef unsigned short u16;
typedef unsigned int u32;
typedef __bf16 bf16x8 __attribute__((ext_vector_type(8)));
typedef float f32x4 __attribute__((ext_vector_type(4)));

#define DEVI static __device__ __forceinline__

// round-to-nearest-even fp32 -> bf16
DEVI u16 f2bf(float f) {
  u32 u = __builtin_bit_cast(u32, f);
  u = (u + 0x7fffu + ((u >> 16) & 1u)) >> 16;
  return (u16)u;
}

// async global->LDS, 16B per lane. LDS dest is wave-uniform base + lane*16.
DEVI void gll16(const void* gsrc, const void* ldst) {
  __builtin_amdgcn_global_load_lds(
      (const __attribute__((address_space(1))) u32*)(uintptr_t)gsrc,
      (__attribute__((address_space(3))) u32*)(u32)(uintptr_t)ldst, 16, 0, 0);
}

DEVI float wredsum(float v) {
  v += __shfl_xor(v, 32); v += __shfl_xor(v, 16); v += __shfl_xor(v, 8);
  v += __shfl_xor(v, 4);  v += __shfl_xor(v, 2);  v += __shfl_xor(v, 1);
  return v;
}

// raw s_barrier with compiler memory fences (no vmcnt drain!)
DEVI void barx() {
  asm volatile("" ::: "memory");
  __builtin_amdgcn_s_barrier();
  asm volatile("" ::: "memory");
}

// ---------------- transpose + cvt: fp32 [R][C] -> bf16 [C][R] ----------------
__global__ __launch_bounds__(256) void k_tcvt(const float* __restrict__ in, u16* __restrict__ out,
                                              int R, int C, long in_z, long out_z) {
  __shared__ float tile[32][33];
  const float* inp = in + (long)blockIdx.z * in_z;
  u16* outp = out + (long)blockIdx.z * out_z;
  int c0 = blockIdx.x * 32, r0 = blockIdx.y * 32;
  int tx = threadIdx.x & 31, ty = threadIdx.x >> 5;
#pragma unroll
  for (int i = 0; i < 4; ++i)
    tile[ty + i * 8][tx] = inp[(long)(r0 + ty + i * 8) * C + c0 + tx];
  __syncthreads();
#pragma unroll
  for (int i = 0; i < 4; ++i) {
    int cc = ty + i * 8;
    outp[(long)(c0 + cc) * R + r0 + tx] = f2bf(tile[tx][cc]);
  }
}

// ---------------- elementwise fp32 -> bf16 ----------------
__global__ __launch_bounds__(256) void k_cvt(const float* __restrict__ in, u16* __restrict__ out, int n4) {
  int i = blockIdx.x * 256 + threadIdx.x;
  if (i >= n4) return;
  float4 v = ((const float4*)in)[i];
  ushort4 o;
  o.x = f2bf(v.x); o.y = f2bf(v.y); o.z = f2bf(v.z); o.w = f2bf(v.w);
  ((ushort4*)out)[i] = o;
}

// ============ 8-phase-style deep-pipelined bf16 GEMM ============
// C = A[M][K] * Bt[N][K]^T (+bias). Tile 256x128, BK=64, 8 waves (4M x 2N),
// per-wave 64x64 output. LDS 96KB: 2 buf x (A 32KB + B 16KB), XOR-swizzled
// (pre-swizzled global source, swizzled ds_read — rule #21 both-sides).
// Stage units (16KB, 2 loads/thread): P1 stages B(x+1); P2 stages Ah0/Ah1(x+2);
// counted s_waitcnt vmcnt(4) once per K-tile (drain only at x=nk-2).
// Split-K via blockIdx z-slice: fp32 partials at Cout + z*pofs.
// EPI: 0 = fp32 out, 1 = bf16+bias, 2 = exact-GELU -> bf16 (+bias)
template <int EPI>
__global__ __launch_bounds__(512, 2) void k_gemm8(const u16* __restrict__ A, const u16* __restrict__ Bt,
                                                  const float* __restrict__ bias, void* __restrict__ Cout,
                                                  long pofs, int M, int N, int K, int Kc) {
  __shared__ __align__(16) u16 lds[49152];  // 96 KB
  char* Lc = (char*)&lds[0];
  const int tid = threadIdx.x;
  const int lane = tid & 63, wid = tid >> 6;
  const int wr = wid >> 1, wc = wid & 1;   // 4 M-waves x 2 N-waves
  const int g = lane >> 4, r16 = lane & 15;

  // bijective XCD swizzle (grid % 8 == 0 for all launches)
  const int gx = N >> 7, gy = M >> 8;
  const int cpx = (int)gridDim.x >> 3;
  int bb = blockIdx.x;
  int id = (bb & 7) * cpx + (bb >> 3);
  const int gxy = gx * gy;
  const int bz = id / gxy;
  int rr = id - bz * gxy;
  const int by = rr / gx;
  const int bx = rr - by * gx;
  const long row0 = (long)by * 256;
  const long col0 = (long)bx * 128;
  const long kbeg = (long)bz * Kc;
  const int nk = Kc >> 6;  // K-tiles of 64 (nk >= 3 required)

  const size_t KB = (size_t)K * 2;  // row stride in bytes
  const char* Ab = (const char*)A + (size_t)row0 * KB + (size_t)kbeg * 2;
  const char* Bb = (const char*)Bt + (size_t)col0 * KB + (size_t)kbeg * 2;

  // stage one 16KB unit (128 rows x 128B): 2 gll16/thread, linear LDS dest,
  // inverse-swizzled global source: src = dest ^ ((destrow&7)<<4)
#define STAGE(gb, ldsoff)                                                        \
  do {                                                                           \
    _Pragma("unroll") for (int i_ = 0; i_ < 2; ++i_) {                           \
      int dq_ = i_ * 8192 + tid * 16;                                            \
      int sq_ = dq_ ^ (((dq_ >> 7) & 7) << 4);                                   \
      gll16((gb) + (size_t)(sq_ >> 7) * KB + (sq_ & 127),                        \
            Lc + (ldsoff) + i_ * 8192 + wid * 1024);                             \
    }                                                                            \
  } while (0)

  f32x4 acc[4][4];
#pragma unroll
  for (int i = 0; i < 4; ++i)
#pragma unroll
    for (int j = 0; j < 4; ++j) acc[i][j] = {0.f, 0.f, 0.f, 0.f};

  // prologue: tile0 {Ah0,Ah1,B} -> buf0; tile1 {Ah0,Ah1} -> buf1 (10 loads)
  STAGE(Ab, 0);
  STAGE(Ab + 128 * KB, 16384);
  STAGE(Bb, 32768);
  STAGE(Ab + 128, 49152);
  STAGE(Ab + 128 * KB + 128, 49152 + 16384);
  asm volatile("s_waitcnt vmcnt(4)" ::: "memory");  // tile0 resident; tile1 A in flight
  barx();

  // per-thread constant addressing: row&7 == r16&7 (all other terms are %8==0)
  const int swz = (r16 & 7) << 4;
  const int arow = (wr >> 1) * 16384 + ((wr & 1) * 64 + r16) * 128;  // + m*2048
  const int brow = 32768 + (wc * 64 + r16) * 128;                    // + n*2048

  for (int x = 0; x < nk; ++x) {
    const int buf = (x & 1) ? 49152 : 0;
    const int obuf = 49152 - buf;
    // -------- P1: read all A-frags + B n0..1; stage B(x+1); MFMA n0..1 --------
    bf16x8 aF[4][2], bF0[2][2];
#pragma unroll
    for (int m = 0; m < 4; ++m)
#pragma unroll
      for (int ks = 0; ks < 2; ++ks)
        aF[m][ks] = *(const bf16x8*)(Lc + buf + arow + m * 2048 + ((ks * 64 + g * 16) ^ swz));
#pragma unroll
    for (int n = 0; n < 2; ++n)
#pragma unroll
      for (int ks = 0; ks < 2; ++ks)
        bF0[n][ks] = *(const bf16x8*)(Lc + buf + brow + n * 2048 + ((ks * 64 + g * 16) ^ swz));
    if (x + 1 < nk) STAGE(Bb + (size_t)(x + 1) * 128, obuf + 32768);
    barx();
    __builtin_amdgcn_s_setprio(1);
#pragma unroll
    for (int ks = 0; ks < 2; ++ks)
#pragma unroll
      for (int m = 0; m < 4; ++m)
#pragma unroll
        for (int n = 0; n < 2; ++n)
          acc[m][n] = __builtin_amdgcn_mfma_f32_16x16x32_bf16(aF[m][ks], bF0[n][ks], acc[m][n], 0, 0, 0);
    __builtin_amdgcn_s_setprio(0);
    barx();  // protects other waves' in-flight P1 ds_reads from P2's A-stage clobber
    // -------- P2: read B n2..3; stage Ah0/Ah1(x+2); counted vmcnt; MFMA n2..3 --------
    bf16x8 bF1[2][2];
#pragma unroll
    for (int n = 0; n < 2; ++n)
#pragma unroll
      for (int ks = 0; ks < 2; ++ks)
        bF1[n][ks] = *(const bf16x8*)(Lc + buf + brow + (n + 2) * 2048 + ((ks * 64 + g * 16) ^ swz));
    if (x + 2 < nk) {
      STAGE(Ab + (size_t)(x + 2) * 128, buf);
      STAGE(Ab + 128 * KB + (size_t)(x + 2) * 128, buf + 16384);
    }
    if (x < nk - 2) {
      asm volatile("s_waitcnt vmcnt(4)" ::: "memory");  // tile x+1 fully resident
    } else if (x == nk - 2) {
      asm volatile("s_waitcnt vmcnt(0)" ::: "memory");  // final drain
    }
    barx();
    __builtin_amdgcn_s_setprio(1);
#pragma unroll
    for (int ks = 0; ks < 2; ++ks)
#pragma unroll
      for (int m = 0; m < 4; ++m)
#pragma unroll
        for (int n = 0; n < 2; ++n)
          acc[m][n + 2] = __builtin_amdgcn_mfma_f32_16x16x32_bf16(aF[m][ks], bF1[n][ks], acc[m][n + 2], 0, 0, 0);
    __builtin_amdgcn_s_setprio(0);
    barx();
  }
#undef STAGE

  // epilogue: C/D mapping col=lane&15, row=(lane>>4)*4+j (verified r1)
  float* outf = (float*)Cout + (long)bz * pofs;
#pragma unroll
  for (int n = 0; n < 4; ++n) {
    long col = col0 + wc * 64 + n * 16 + r16;
    float bv = bias ? bias[col] : 0.f;
#pragma unroll
    for (int m = 0; m < 4; ++m) {
      long rowb = row0 + wr * 64 + m * 16 + g * 4;
#pragma unroll
      for (int j = 0; j < 4; ++j) {
        float v = acc[m][n][j] + bv;
        size_t off = (size_t)(rowb + j) * N + col;
        if (EPI == 0) {
          outf[off] = v;
        } else if (EPI == 1) {
          ((u16*)Cout)[off] = f2bf(v);
        } else {
          float gl = 0.5f * v * (1.f + erff(v * 0.70710678118f));
          ((u16*)Cout)[off] = f2bf(gl);
        }
      }
    }
  }
}

// ---------------- build V^T: qkvb[token][2048+h*64+p] -> vt[(b,h)][p][s] ----------------
__global__ __launch_bounds__(256) void k_build_vt(const u16* __restrict__ qkvb, u16* __restrict__ vt) {
  __shared__ u16 tile[32][33];
  int z = blockIdx.z, b = z >> 4, h = z & 15;
  int p0 = blockIdx.x * 32, s0 = blockIdx.y * 32;
  int tx = threadIdx.x & 31, ty = threadIdx.x >> 5;
#pragma unroll
  for (int i = 0; i < 4; ++i) {
    int s = s0 + ty + i * 8;
    tile[ty + i * 8][tx] = qkvb[(size_t)(b * 512 + s) * 3072 + 2048 + h * 64 + p0 + tx];
  }
  __syncthreads();
#pragma unroll
  for (int i = 0; i < 4; ++i) {
    int p = ty + i * 8;
    vt[((size_t)z * 64 + p0 + p) * 512 + s0 + tx] = tile[tx][p];
  }
}

// ---------------- fused flash attention ----------------
__global__ __launch_bounds__(256) void k_attn(const u16* __restrict__ qkvb, const u16* __restrict__ vt,
                                              u16* __restrict__ ctxb) {
  __shared__ __align__(16) u16 Qs[64 * 64];
  __shared__ __align__(16) u16 Ks[64 * 64];
  __shared__ __align__(16) u16 Vts[64 * 64];
  __shared__ __align__(16) u16 Ps[4 * 16 * 64];
  const int tid = threadIdx.x, lane = tid & 63, wid = tid >> 6;
  const int g = lane >> 4, r16 = lane & 15;
  const int z = blockIdx.y, b = z >> 4, h = z & 15;
  const int qt = blockIdx.x;
  const float CF = 0.125f * 1.44269504089f;

#pragma unroll
  for (int it = 0; it < 2; ++it) {
    int q = it * 4096 + tid * 16;
    int row = q >> 7, colb = q & 127;
    int scol = colb ^ ((row & 7) << 4);
    gll16((const char*)qkvb + ((size_t)(b * 512 + qt * 64 + row) * 3072 + h * 64) * 2 + scol,
          (const char*)Qs + it * 4096 + wid * 1024);
  }
  __syncthreads();
  bf16x8 aq[2];
  {
    int rowl = wid * 16 + r16;
#pragma unroll
    for (int kk = 0; kk < 2; ++kk)
      aq[kk] = *(const bf16x8*)(Qs + rowl * 64 + ((kk * 32 + g * 8) ^ ((rowl & 7) << 3)));
  }

  f32x4 o[4];
#pragma unroll
  for (int pi = 0; pi < 4; ++pi) o[pi] = {0.f, 0.f, 0.f, 0.f};
  float m4[4], l4[4];
#pragma unroll
  for (int j = 0; j < 4; ++j) { m4[j] = -1e30f; l4[j] = 0.f; }

  for (int kt = 0; kt < 8; ++kt) {
#pragma unroll
    for (int it = 0; it < 2; ++it) {
      int q = it * 4096 + tid * 16;
      int row = q >> 7, colb = q & 127;
      int scol = colb ^ ((row & 7) << 4);
      gll16((const char*)qkvb + ((size_t)(b * 512 + kt * 64 + row) * 3072 + 1024 + h * 64) * 2 + scol,
            (const char*)Ks + it * 4096 + wid * 1024);
      gll16((const char*)vt + ((size_t)(z * 64 + row) * 512 + kt * 64) * 2 + scol,
            (const char*)Vts + it * 4096 + wid * 1024);
    }
    __syncthreads();

    f32x4 s[4];
#pragma unroll
    for (int nj = 0; nj < 4; ++nj) s[nj] = {0.f, 0.f, 0.f, 0.f};
#pragma unroll
    for (int kk = 0; kk < 2; ++kk) {
#pragma unroll
      for (int nj = 0; nj < 4; ++nj) {
        int rowk = nj * 16 + r16;
        bf16x8 bk = *(const bf16x8*)(Ks + rowk * 64 + ((kk * 32 + g * 8) ^ ((rowk & 7) << 3)));
        s[nj] = __builtin_amdgcn_mfma_f32_16x16x32_bf16(aq[kk], bk, s[nj], 0, 0, 0);
      }
    }

    float scale[4];
#pragma unroll
    for (int j = 0; j < 4; ++j) {
      float pm = fmaxf(fmaxf(s[0][j], s[1][j]), fmaxf(s[2][j], s[3][j]));
      pm = fmaxf(pm, __shfl_xor(pm, 1));
      pm = fmaxf(pm, __shfl_xor(pm, 2));
      pm = fmaxf(pm, __shfl_xor(pm, 4));
      pm = fmaxf(pm, __shfl_xor(pm, 8));
      float mn = fmaxf(m4[j], pm);
      scale[j] = exp2f((m4[j] - mn) * CF);
      m4[j] = mn;
      int rowp = g * 4 + j;
      u16* pbase = Ps + wid * 1024 + rowp * 64;
      int sw = (rowp & 7) << 3;
      float ps = 0.f;
#pragma unroll
      for (int nj = 0; nj < 4; ++nj) {
        float p = exp2f((s[nj][j] - mn) * CF);
        ps += p;
        pbase[(nj * 16 + r16) ^ sw] = f2bf(p);
      }
      ps += __shfl_xor(ps, 1); ps += __shfl_xor(ps, 2);
      ps += __shfl_xor(ps, 4); ps += __shfl_xor(ps, 8);
      l4[j] = l4[j] * scale[j] + ps;
    }
#pragma unroll
    for (int pi = 0; pi < 4; ++pi)
#pragma unroll
      for (int j = 0; j < 4; ++j) o[pi][j] *= scale[j];

    asm volatile("s_waitcnt lgkmcnt(0)" ::: "memory");

#pragma unroll
    for (int kk = 0; kk < 2; ++kk) {
      bf16x8 ap = *(const bf16x8*)(Ps + wid * 1024 + r16 * 64 + ((kk * 32 + g * 8) ^ ((r16 & 7) << 3)));
#pragma unroll
      for (int pi = 0; pi < 4; ++pi) {
        int rowv = pi * 16 + r16;
        bf16x8 bv = *(const bf16x8*)(Vts + rowv * 64 + ((kk * 32 + g * 8) ^ ((rowv & 7) << 3)));
        o[pi] = __builtin_amdgcn_mfma_f32_16x16x32_bf16(ap, bv, o[pi], 0, 0, 0);
      }
    }
    __syncthreads();
  }

#pragma unroll
  for (int j = 0; j < 4; ++j) {
    float inv = 1.f / l4[j];
    int token = b * 512 + qt * 64 + wid * 16 + g * 4 + j;
#pragma unroll
    for (int pi = 0; pi < 4; ++pi)
      ctxb[(size_t)token * 1024 + h * 64 + pi * 16 + r16] = f2bf(o[pi][j] * inv);
  }
}

// ---------------- fused (2-partial sum) + bias + residual + LayerNorm ----------------
__global__ __launch_bounds__(256) void k_ln3(const float* __restrict__ a0, const float* __restrict__ a1,
                                             const float* __restrict__ res, const float* __restrict__ bvec,
                                             const float* __restrict__ gamma, const float* __restrict__ beta,
                                             float* __restrict__ outf, u16* __restrict__ outb) {
  __shared__ float sb[8];
  int row = blockIdx.x, t = threadIdx.x, lane = t & 63, wid = t >> 6;
  const float* p0 = a0 + (size_t)row * 1024;
  const float* p1 = a1 + (size_t)row * 1024;
  const float* pr = res + (size_t)row * 1024;
  float v[4];
  float s = 0.f;
#pragma unroll
  for (int i = 0; i < 4; ++i) {
    int c = i * 256 + t;
    v[i] = p0[c] + p1[c] + pr[c] + bvec[c];
    s += v[i];
  }
  s = wredsum(s);
  if (lane == 0) sb[wid] = s;
  __syncthreads();
  float mu = (sb[0] + sb[1] + sb[2] + sb[3]) * (1.f / 1024.f);
  float q = 0.f;
#pragma unroll
  for (int i = 0; i < 4; ++i) { float d = v[i] - mu; q += d * d; }
  q = wredsum(q);
  if (lane == 0) sb[4 + wid] = q;
  __syncthreads();
  float rstd = rsqrtf((sb[4] + sb[5] + sb[6] + sb[7]) * (1.f / 1024.f) + 1e-5f);
#pragma unroll
  for (int i = 0; i < 4; ++i) {
    int c = i * 256 + t;
    float ov = (v[i] - mu) * rstd * gamma[c] + beta[c];
    outf[(size_t)row * 1024 + c] = ov;
    if (outb) outb[(size_t)row * 1024 + c] = f2bf(ov);
  }
}

// ---------------- orchestration ----------------
// Workspace map (MB), time-multiplexed (same as R2):
//   [0,6) wqkvb -> ffn2 p1 [0,16) | [6,8) woutb | [8,16) wffn1b | [16,24) wffn2b
//   [24,32) xb/ctxb/r1b | [32,56) qkvb -> q1 [32,48) -> hb [32,64)
//   [56,64) vt | [64,80) q0 -> p0 | r1 fp32 in d_out. Peak 80 MB.
extern "C" void kernel_launch(void* const* d_in, const int* in_sizes, int n_in,
                              void* d_out, int out_size, void* d_ws, size_t ws_size,
                              hipStream_t stream) {
  const float* x      = (const float*)d_in[0];
  const float* w_qkv  = (const float*)d_in[1];
  const float* b_qkv  = (const float*)d_in[2];
  const float* w_out  = (const float*)d_in[3];
  const float* b_out  = (const float*)d_in[4];
  const float* ln1s   = (const float*)d_in[5];
  const float* ln1b   = (const float*)d_in[6];
  const float* w_ffn1 = (const float*)d_in[7];
  const float* b_ffn1 = (const float*)d_in[8];
  const float* w_ffn2 = (const float*)d_in[9];
  const float* b_ffn2 = (const float*)d_in[10];
  const float* ln2s   = (const float*)d_in[11];
  const float* ln2b   = (const float*)d_in[12];

  char* ws = (char*)d_ws;
  const size_t MB = 1024 * 1024;
  u16* wqkvb   = (u16*)(ws + 0 * MB);
  u16* woutb   = (u16*)(ws + 6 * MB);
  u16* wffn1b  = (u16*)(ws + 8 * MB);
  u16* wffn2b  = (u16*)(ws + 16 * MB);
  u16* xb      = (u16*)(ws + 24 * MB);
  u16* ctxb    = xb;
  u16* r1b     = xb;
  u16* qkvb    = (u16*)(ws + 32 * MB);
  u16* hb      = (u16*)(ws + 32 * MB);
  u16* vt      = (u16*)(ws + 56 * MB);
  float* q0    = (float*)(ws + 64 * MB);
  float* q1    = (float*)(ws + 32 * MB);
  float* p0    = (float*)(ws + 64 * MB);
  float* p1    = (float*)(ws + 0 * MB);
  float* r1    = (float*)d_out;
  float* outp  = (float*)d_out;

  // pack weights (transpose to [N][K] bf16)
  k_tcvt<<<dim3(32, 32, 3), 256, 0, stream>>>(w_qkv, wqkvb, 1024, 1024, 1024 * 1024, 1024 * 1024);
  k_tcvt<<<dim3(32, 32, 1), 256, 0, stream>>>(w_out, woutb, 1024, 1024, 0, 0);
  k_tcvt<<<dim3(128, 32, 1), 256, 0, stream>>>(w_ffn1, wffn1b, 1024, 4096, 0, 0);
  k_tcvt<<<dim3(32, 128, 1), 256, 0, stream>>>(w_ffn2, wffn2b, 4096, 1024, 0, 0);
  k_cvt<<<4096, 256, 0, stream>>>(x, xb, 1048576);

  // qkv = x @ w_qkv + b_qkv  (bf16 out): grid 24x16 = 384 blocks, nk=16
  k_gemm8<1><<<dim3(24 * 16), 512, 0, stream>>>(xb, wqkvb, b_qkv, qkvb, 0, 4096, 3072, 1024, 1024);
  k_build_vt<<<dim3(2, 16, 128), 256, 0, stream>>>(qkvb, vt);
  k_attn<<<dim3(8, 128), 256, 0, stream>>>(qkvb, vt, ctxb);

  // attn_out = ctx @ w_out (split-K=2: 8x16x2 = 256 blocks, nk=8)
  k_gemm8<0><<<dim3(8 * 16 * 2), 512, 0, stream>>>(ctxb, woutb, nullptr, q0, (long)(q1 - q0),
                                                   4096, 1024, 1024, 512);
  // r1 = LN(x + q0 + q1 + b_out) -> fp32 (d_out) + bf16
  k_ln3<<<4096, 256, 0, stream>>>(q0, q1, x, b_out, ln1s, ln1b, r1, r1b);

  // h = gelu(r1 @ w_ffn1 + b_ffn1): grid 32x16 = 512 blocks, nk=16
  k_gemm8<2><<<dim3(32 * 16), 512, 0, stream>>>(r1b, wffn1b, b_ffn1, hb, 0, 4096, 4096, 1024, 1024);

  // ffn_out = h @ w_ffn2 (split-K=2: 256 blocks, nk=32)
  k_gemm8<0><<<dim3(8 * 16 * 2), 512, 0, stream>>>(hb, wffn2b, nullptr, p0, (long)(p1 - p0),
                                                   4096, 1024, 4096, 2048);
  // out = LN(r1 + p0 + p1 + b_ffn2)
  k_ln3<<<4096, 256, 0, stream>>>(p0, p1, r1, b_ffn2, ln2s, ln2b, outp, (u16*)nullptr);
}